// Round 1
// baseline (182.526 us; speedup 1.0000x reference)
//
#include <hip/hip_runtime.h>
#include <hip/hip_fp16.h>
#include <math.h>

#define HW    2304      // 48*48
#define NPOS  442368    // 192*48*48

typedef _Float16 f16x8 __attribute__((ext_vector_type(8)));
typedef __fp16   h16x2 __attribute__((ext_vector_type(2)));
typedef float    f32x4 __attribute__((ext_vector_type(4)));

__device__ __forceinline__ float phi_f(float z) {
    return 0.5f * (1.0f + erff(z * 0.70710678118654752f));
}
__device__ __forceinline__ unsigned short f2h(float v) {
    _Float16 h = (_Float16)v;
    return *reinterpret_cast<unsigned short*>(&h);
}
__device__ __forceinline__ unsigned int pk2(float a, float b) {
    return (unsigned int)f2h(a) | ((unsigned int)f2h(b) << 16);
}
__device__ __forceinline__ unsigned int pkrtz(float a, float b) {
    h16x2 h = __builtin_amdgcn_cvt_pkrtz(a, b);
    return *reinterpret_cast<unsigned int*>(&h);
}

// ---------------- prep_all: hyperTp transpose + apack + pk + xhp ---------------
// blocks [0,948): hyperTp ; [948,3540): apack ; [3540,3700): pk ; rest: xhp
__global__ __launch_bounds__(256) void prep_all(const float* __restrict__ hyper,
                                                const float* __restrict__ W3,
                                                const float* __restrict__ W1,
                                                const float* __restrict__ Wa,
                                                const float* __restrict__ ba,
                                                const float* __restrict__ b1,
                                                const float* __restrict__ Wb,
                                                const float* __restrict__ bb,
                                                const float* __restrict__ Wc,
                                                const float* __restrict__ xg,
                                                unsigned short* __restrict__ hyperTp,
                                                unsigned short* __restrict__ apack,
                                                unsigned short* __restrict__ pk,
                                                unsigned short* __restrict__ xhp) {
    const int bx = blockIdx.x;
    if (bx < 948) {                        // ---- hyperTp (948 = 79 x 12)
        __shared__ float s[32][33];
        const int pt = bx % 79, it = bx / 79;
        const int tid = threadIdx.x;
        const int c = tid & 31, r = tid >> 5;
        const int pp = pt * 32 + c;
        const int yp = pp / 50, xp = pp % 50;
        const bool inter = (pp < 2500) && yp >= 1 && yp <= 48 && xp >= 1 && xp <= 48;
        const int src = inter ? ((yp - 1) * 48 + (xp - 1)) : 0;
#pragma unroll
        for (int i = 0; i < 4; ++i) {
            int icl = r + i * 8;
            s[icl][c] = inter ? hyper[(size_t)(it * 32 + icl) * HW + src] : 0.f;
        }
        __syncthreads();
#pragma unroll
        for (int i = 0; i < 4; ++i) {
            int pl = r + i * 8;
            int pp2 = pt * 32 + pl;
            if (pp2 < 2500)
                hyperTp[(size_t)pp2 * 384 + it * 32 + c] = f2h(s[c][pl]);
        }
    } else if (bx < 3540) {                // ---- apack: W3 -> 16-oc MFMA tiles
        int idx = (bx - 948) * 256 + threadIdx.x;  // 663552 total
        int j = idx & 7;
        int l = (idx >> 3) & 63;
        int rest = idx >> 9;
        int t = rest % 9; rest /= 9;
        int c = rest % 12; int T = rest / 12;
        int oc = T * 16 + (l & 15);
        int ic = c * 32 + (l >> 4) * 8 + j;
        apack[idx] = f2h(W3[((size_t)oc * 384 + ic) * 9 + t]);
    } else if (bx < 3700) {                // ---- pk: W1 masked + Wa/Wb/Wc folded
        int idx = (bx - 3540) * 256 + threadIdx.x;
        if (idx >= 40960) return;
        float v = 0.f;
        if (idx < 31744) {
            int j = idx & 7, lane = (idx >> 3) & 63, s = (idx >> 9) & 1, c = idx >> 10;
            int q = lane >> 4;
            int oc = s * 16 + (lane & 15);
            int r = 2 * c + (q >> 1), h = q & 1, kw = 8 * h + j;
            if (oc < 24 && r < 61 && kw < 11) {
                int kd = r / 11, kh = r % 11;
                int tap = kd * 121 + kh * 11 + kw;
                if (tap < 665) v = W1[oc * 1331 + tap];
            }
        } else if (idx < 33280) {
            int i2 = idx - 31744;
            int j = i2 & 7, lane = (i2 >> 3) & 63, t = i2 >> 9;
            int m = t * 16 + (lane & 15), k = (lane >> 4) * 8 + j;
            if (k < 25) v = Wa[m * 25 + k];
            else if (k == 25) {
                float s = ba[m];
                for (int c = 0; c < 24; ++c) s += Wa[m * 25 + c] * b1[c];
                v = s;
            }
        } else if (idx < 39424) {
            int i3 = idx - 33280;
            int j = i3 & 7, lane = (i3 >> 3) & 63, k2 = (i3 >> 9) & 1, s = i3 >> 10;
            int m = s * 16 + (lane & 15), ch = k2 * 32 + (lane >> 4) * 8 + j;
            if (ch < 48) v = Wb[m * 48 + ch];
            else if (ch == 48) v = bb[m];
        } else {
            int i4 = idx - 39424;
            int j = i4 & 7, lane = (i4 >> 3) & 63, k3 = i4 >> 9;
            int m = lane & 15, ch = k3 * 32 + (lane >> 4) * 8 + j;
            if (m < 9) v = Wc[m * 96 + ch];
        }
        pk[idx] = f2h(v);
    } else {                               // ---- xhp: padded fp16 volume
        int idx = (bx - 3700) * 256 + threadIdx.x;   // 187456 uint2
        if (idx >= 187456) return;
        int si = idx * 4;
        int zp = si / 3712, rem = si - zp * 3712;
        int yp = rem >> 6, xp0 = rem & 63;
        float f[4];
#pragma unroll
        for (int k = 0; k < 4; ++k) {
            int xp = xp0 + k;
            bool in = zp >= 5 && zp < 197 && yp >= 5 && yp < 53 && xp >= 5 && xp < 53;
            f[k] = in ? xg[(size_t)(zp - 5) * HW + (yp - 5) * 48 + (xp - 5)] : 0.f;
        }
        *(uint2*)&xhp[si] = make_uint2(pk2(f[0], f[1]), pk2(f[2], f[3]));
    }
}

// ---------------- fused3: conv2d(in-block) + conv3d + MLP + likelihood --------
// 1728 blocks x 256 thr. Block tile: 16 d x 4 y x 4 x. Wave w <-> y row.
__global__ __launch_bounds__(256) void fused3(const unsigned short* __restrict__ xhp,
                                              const unsigned short* __restrict__ pk,
                                              const unsigned short* __restrict__ hyperTp,
                                              const unsigned short* __restrict__ apack,
                                              const float* __restrict__ b3,
                                              const float* __restrict__ xg,
                                              const float* __restrict__ bc,
                                              float* __restrict__ out) {
    // P: patch (294 rows x 16 sh = 4704) then acc staging [64][104] (6656)
    __shared__ __align__(16) unsigned short P[6656];
    __shared__ __align__(16) unsigned short t1s[4][1152];   // [wave][16 pos][72]
    __shared__ __align__(16) unsigned short t2s[4][1664];   // [wave][16 pos][104]
    __shared__ __align__(16) float fscr[3328];              // hpart[1024] U oacs[4*64*13]
    __shared__ __align__(16) float htile[256];              // [oc16][pos16] conv2d h

    const int tid = threadIdx.x, w = tid >> 6, lane = tid & 63;
    const int n = lane & 15, q = lane >> 4;
    const int bx = blockIdx.x;
    const int x0 = (bx % 12) * 4, y0 = ((bx / 12) % 12) * 4;
    const int T = bx / 144, d0 = T * 16;

    // ---- stage conv3d patch: 294 rows x 2 uint4 (row = py*21+pz, 16 shorts)
#pragma unroll
    for (int k = 0; k < 3; ++k) {
        int idx = tid + k * 256;
        if (idx < 588) {
            int row = idx >> 1, half = idx & 1;
            int py = row / 21, pz = row - py * 21;
            const uint4* src = (const uint4*)(xhp + ((size_t)(d0 + pz) * 58 + (y0 + py)) * 64
                                              + x0 + half * 8);
            *(uint4*)&P[row * 16 + half * 8] = *src;
        }
    }

    // ---- conv2d partials: wave w handles ic-groups c = 3w..3w+2 (16 oc x 16 px)
    {
        f32x4 hacc = {0.f, 0.f, 0.f, 0.f};
        const int pp = (y0 + (n >> 2)) * 50 + x0 + (n & 3);   // pos n = (yloc, xloc)
        const size_t bbase = (size_t)pp * 384 + q * 8;
        for (int cc = 0; cc < 3; ++cc) {
            const int c = w * 3 + cc;
            const unsigned short* ap = apack + ((size_t)(T * 12 + c) * 9) * 512 + lane * 8;
            const int coff = c * 32;
#pragma unroll
            for (int t = 0; t < 9; ++t) {
                f16x8 a = *(const f16x8*)(ap + t * 512);
                const int dd = (t / 3) * 50 + (t % 3);        // compile-time
                f16x8 b = *(const f16x8*)(hyperTp + bbase + (size_t)dd * 384 + coff);
                hacc = __builtin_amdgcn_mfma_f32_16x16x32_f16(a, b, hacc, 0, 0, 0);
            }
        }
#pragma unroll
        for (int e = 0; e < 4; ++e)
            fscr[w * 256 + (q * 4 + e) * 16 + n] = hacc[e];   // hpart[w][oc][pos]
    }
    __syncthreads();   // patch staged + hpart complete

    // ---- htile reduce: one (oc,pos) per thread; + b3 fold
    {
        const int oc = tid >> 4, pos = tid & 15;
        float h = b3[d0 + oc];
#pragma unroll
        for (int ww = 0; ww < 4; ++ww) h += fscr[ww * 256 + oc * 16 + pos];
        htile[oc * 16 + pos] = h;
    }

    // ---- conv3d main loop, register-double-buffered B (prefetch c+1's LDS rows)
    const f32x4 zf = {0.f, 0.f, 0.f, 0.f};
    f32x4 acc[4][2];
#pragma unroll
    for (int p = 0; p < 4; ++p) { acc[p][0] = zf; acc[p][1] = zf; }

    const f16x8* Av = (const f16x8*)pk;
    f16x8 a0 = Av[lane], a1 = Av[64 + lane];
    unsigned int u[6];
    {
        const int r0 = (q >> 1);
        const int kd = r0 / 11, kh = r0 - kd * 11;
        const unsigned short* rp = P + ((w + kh) * 21 + (n + kd)) * 16 + (q & 1) * 8;
        *(uint4*)&u[0] = *(const uint4*)rp;
        *(uint2*)&u[4] = *(const uint2*)(rp + 8);
    }
    for (int c = 0; c < 31; ++c) {
        // prefetch next iteration's B rows (c=30 -> r=62/63: in-bounds, discarded)
        unsigned int u2[6];
        {
            const int r = 2 * (c + 1) + (q >> 1);
            const int kd = r / 11, kh = r - kd * 11;
            const unsigned short* rp = P + ((w + kh) * 21 + (n + kd)) * 16 + (q & 1) * 8;
            *(uint4*)&u2[0] = *(const uint4*)rp;
            *(uint2*)&u2[4] = *(const uint2*)(rp + 8);
        }
        f16x8 ca0 = a0, ca1 = a1;
        const int cn = (c < 30) ? c + 1 : 30;
        a0 = Av[cn * 128 + lane];
        a1 = Av[cn * 128 + 64 + lane];
#pragma unroll
        for (int px = 0; px < 4; ++px) {
            unsigned int bw[4];
#pragma unroll
            for (int i = 0; i < 4; ++i) {
                if ((px & 1) == 0) bw[i] = u[(px >> 1) + i];
                else bw[i] = (u[(px >> 1) + i] >> 16) | (u[(px >> 1) + 1 + i] << 16);
            }
            f16x8 bf = *(f16x8*)bw;
            acc[px][0] = __builtin_amdgcn_mfma_f32_16x16x32_f16(ca0, bf, acc[px][0], 0, 0, 0);
            acc[px][1] = __builtin_amdgcn_mfma_f32_16x16x32_f16(ca1, bf, acc[px][1], 0, 0, 0);
        }
#pragma unroll
        for (int i = 0; i < 6; ++i) u[i] = u2[i];
    }
    __syncthreads();   // patch consumed (htile also globally visible after this)

    // ---- stage acc -> P as [64 pos][104]: pos row = w*16+n (wave-local), 24 oc x 4 px
#pragma unroll
    for (int px = 0; px < 4; ++px) {
        unsigned int lo = pk2(acc[px][0][0], acc[px][0][1]);
        unsigned int hi = pk2(acc[px][0][2], acc[px][0][3]);
        *(uint2*)&P[(w * 16 + n) * 104 + px * 24 + q * 4] = make_uint2(lo, hi);
        if (q < 2) {
            unsigned int l2 = pk2(acc[px][1][0], acc[px][1][1]);
            unsigned int h2 = pk2(acc[px][1][2], acc[px][1][3]);
            *(uint2*)&P[(w * 16 + n) * 104 + px * 24 + 16 + q * 4] = make_uint2(l2, h2);
        }
    }
    // everything below is wave-local in LDS: no further barriers needed

    // ---- MLP (per wave: 4 groups of 16 positions, group = px)
    // volatile: keep weight fragments OUT of registers during conv3d (prevents LICM hoist)
    const volatile f16x8* WaF = (const volatile f16x8*)(pk + 31744);
    const volatile f16x8* WbF = (const volatile f16x8*)(pk + 33280);
    const volatile f16x8* WcF = (const volatile f16x8*)(pk + 39424);
    float bcv[4];
#pragma unroll
    for (int e = 0; e < 4; ++e) bcv[e] = (q * 4 + e < 9) ? bc[q * 4 + e] : 0.f;
    // t1 const slot: feature 48 = 1.0, 49..63 = 0 (written once, layer a only touches 0..47)
    *(uint2*)&t1s[w][n * 72 + 48 + q * 4] = make_uint2((q == 0) ? 0x00003C00u : 0u, 0u);

    const f16x8 z8 = {};
    for (int px = 0; px < 4; ++px) {
        f16x8 b0;
        if (q < 3) {
            b0 = *(const f16x8*)&P[(w * 16 + n) * 104 + px * 24 + q * 8];
        } else {
            b0 = z8;
            b0[0] = (_Float16)htile[n * 16 + w * 4 + px];   // h feature (k=24)
            b0[1] = (_Float16)1.0f;                          // const (k=25)
        }
        // layer a: 25(+h+const) -> 48
#pragma unroll
        for (int s = 0; s < 3; ++s) {
            f16x8 a = WaF[s * 64 + lane];
            f32x4 r1 = __builtin_amdgcn_mfma_f32_16x16x32_f16(a, b0, zf, 0, 0, 0);
            *(uint2*)&t1s[w][n * 72 + s * 16 + q * 4] =
                make_uint2(pkrtz(fmaxf(r1[0], 0.f), fmaxf(r1[1], 0.f)),
                           pkrtz(fmaxf(r1[2], 0.f), fmaxf(r1[3], 0.f)));
        }
        // layer b: 48(+const) -> 96
        f32x4 rb[6];
#pragma unroll
        for (int s = 0; s < 6; ++s) rb[s] = zf;
#pragma unroll
        for (int k2 = 0; k2 < 2; ++k2) {
            f16x8 bf = *(const f16x8*)&t1s[w][n * 72 + k2 * 32 + q * 8];
#pragma unroll
            for (int s = 0; s < 6; ++s) {
                f16x8 a = WbF[(s * 2 + k2) * 64 + lane];
                rb[s] = __builtin_amdgcn_mfma_f32_16x16x32_f16(a, bf, rb[s], 0, 0, 0);
            }
        }
#pragma unroll
        for (int s = 0; s < 6; ++s)
            *(uint2*)&t2s[w][n * 104 + s * 16 + q * 4] =
                make_uint2(pkrtz(fmaxf(rb[s][0], 0.f), fmaxf(rb[s][1], 0.f)),
                           pkrtz(fmaxf(rb[s][2], 0.f), fmaxf(rb[s][3], 0.f)));
        // layer c: 96 -> 9
        f32x4 rc = zf;
#pragma unroll
        for (int k3 = 0; k3 < 3; ++k3) {
            f16x8 bf = *(const f16x8*)&t2s[w][n * 104 + k3 * 32 + q * 8];
            f16x8 a = WcF[k3 * 64 + lane];
            rc = __builtin_amdgcn_mfma_f32_16x16x32_f16(a, bf, rc, 0, 0, 0);
        }
#pragma unroll
        for (int e = 0; e < 4; ++e) {
            const int row = q * 4 + e;
            if (row < 9) fscr[w * 832 + (n * 4 + px) * 13 + row] = rc[e] + bcv[e];
        }
    }

    // ---- likelihood: all 64 lanes, lane l -> pos (d = d0 + l>>2, y = y0+w, x = x0 + (l&3))
    {
        float o[9];
#pragma unroll
        for (int jj = 0; jj < 9; ++jj) o[jj] = fscr[w * 832 + lane * 13 + jj];
        const int gp = (d0 + (lane >> 2)) * HW + (y0 + w) * 48 + x0 + (lane & 3);
        const float xv = xg[gp];
        float m = fmaxf(o[6], fmaxf(o[7], o[8]));
        float e0 = expf(o[6] - m), e1 = expf(o[7] - m), e2 = expf(o[8] - m);
        float inv_es = 1.0f / (e0 + e1 + e2);
        float p = 0.f;
#pragma unroll
        for (int jj = 0; jj < 3; ++jj) {
            float mu = o[jj];
            float sc = o[3 + jj];
            sc = (sc == 0.0f) ? 1e-9f : sc;
            sc = fabsf(sc);
            float a = phi_f((xv + 0.5f - mu) / sc);
            float b = phi_f((xv - 0.5f - mu) / sc);
            float lik = fabsf(a - b);
            float wgt = ((jj == 0) ? e0 : (jj == 1) ? e1 : e2) * inv_es;
            p = fmaf(wgt, lik, p);
        }
        out[gp] = p;
#pragma unroll
        for (int jj = 0; jj < 9; ++jj) out[NPOS + (size_t)jj * NPOS + gp] = o[jj];
    }
}

extern "C" void kernel_launch(void* const* d_in, const int* in_sizes, int n_in,
                              void* d_out, int out_size, void* d_ws, size_t ws_size,
                              hipStream_t stream) {
    const float* x     = (const float*)d_in[0];
    const float* hyper = (const float*)d_in[1];
    const float* W3    = (const float*)d_in[2];
    const float* b3    = (const float*)d_in[3];
    const float* W1    = (const float*)d_in[4];
    const float* b1    = (const float*)d_in[5];
    const float* Wa    = (const float*)d_in[6];
    const float* ba    = (const float*)d_in[7];
    const float* Wb    = (const float*)d_in[8];
    const float* bb    = (const float*)d_in[9];
    const float* Wc    = (const float*)d_in[10];
    const float* bc    = (const float*)d_in[11];
    float* out = (float*)d_out;

    unsigned short* hyperTp = (unsigned short*)d_ws;           // 960000 f16
    unsigned short* apack   = hyperTp + 960000;                // 663552 f16
    unsigned short* pk      = apack + 663552;                  // 40960 f16
    unsigned short* xhp     = pk + 40960;                      // 749824 f16 (padded x)

    prep_all<<<4433, 256, 0, stream>>>(hyper, W3, W1, Wa, ba, b1, Wb, bb, Wc, x,
                                       hyperTp, apack, pk, xhp);
    fused3<<<1728, 256, 0, stream>>>(xhp, pk, hyperTp, apack, b3, x, bc, out);
}

// Round 2
// 151.819 us; speedup vs baseline: 1.2023x; 1.2023x over previous
//
#include <hip/hip_runtime.h>
#include <hip/hip_fp16.h>
#include <math.h>

#define HW    2304      // 48*48
#define NPOS  442368    // 192*48*48

typedef _Float16 f16x8 __attribute__((ext_vector_type(8)));
typedef __fp16   h16x2 __attribute__((ext_vector_type(2)));
typedef float    f32x4 __attribute__((ext_vector_type(4)));

__device__ __forceinline__ float phi_f(float z) {
    return 0.5f * (1.0f + erff(z * 0.70710678118654752f));
}
__device__ __forceinline__ unsigned short f2h(float v) {
    _Float16 h = (_Float16)v;
    return *reinterpret_cast<unsigned short*>(&h);
}
__device__ __forceinline__ unsigned int pk2(float a, float b) {
    return (unsigned int)f2h(a) | ((unsigned int)f2h(b) << 16);
}
__device__ __forceinline__ unsigned int pkrtz(float a, float b) {
    h16x2 h = __builtin_amdgcn_cvt_pkrtz(a, b);
    return *reinterpret_cast<unsigned int*>(&h);
}

// ---------------- prep_all: hyperTp transpose + apack + pk + xhp ---------------
// blocks [0,948): hyperTp ; [948,3540): apack ; [3540,3700): pk ; rest: xhp
__global__ __launch_bounds__(256) void prep_all(const float* __restrict__ hyper,
                                                const float* __restrict__ W3,
                                                const float* __restrict__ W1,
                                                const float* __restrict__ Wa,
                                                const float* __restrict__ ba,
                                                const float* __restrict__ b1,
                                                const float* __restrict__ Wb,
                                                const float* __restrict__ bb,
                                                const float* __restrict__ Wc,
                                                const float* __restrict__ xg,
                                                unsigned short* __restrict__ hyperTp,
                                                unsigned short* __restrict__ apack,
                                                unsigned short* __restrict__ pk,
                                                unsigned short* __restrict__ xhp) {
    const int bx = blockIdx.x;
    if (bx < 948) {                        // ---- hyperTp (948 = 79 x 12)
        __shared__ float s[32][33];
        const int pt = bx % 79, it = bx / 79;
        const int tid = threadIdx.x;
        const int c = tid & 31, r = tid >> 5;
        const int pp = pt * 32 + c;
        const int yp = pp / 50, xp = pp % 50;
        const bool inter = (pp < 2500) && yp >= 1 && yp <= 48 && xp >= 1 && xp <= 48;
        const int src = inter ? ((yp - 1) * 48 + (xp - 1)) : 0;
#pragma unroll
        for (int i = 0; i < 4; ++i) {
            int icl = r + i * 8;
            s[icl][c] = inter ? hyper[(size_t)(it * 32 + icl) * HW + src] : 0.f;
        }
        __syncthreads();
#pragma unroll
        for (int i = 0; i < 4; ++i) {
            int pl = r + i * 8;
            int pp2 = pt * 32 + pl;
            if (pp2 < 2500)
                hyperTp[(size_t)pp2 * 384 + it * 32 + c] = f2h(s[c][pl]);
        }
    } else if (bx < 3540) {                // ---- apack: W3 -> 16-oc MFMA tiles
        int idx = (bx - 948) * 256 + threadIdx.x;  // 663552 total
        int j = idx & 7;
        int l = (idx >> 3) & 63;
        int rest = idx >> 9;
        int t = rest % 9; rest /= 9;
        int c = rest % 12; int T = rest / 12;
        int oc = T * 16 + (l & 15);
        int ic = c * 32 + (l >> 4) * 8 + j;
        apack[idx] = f2h(W3[((size_t)oc * 384 + ic) * 9 + t]);
    } else if (bx < 3700) {                // ---- pk: W1 masked + Wa/Wb/Wc folded
        int idx = (bx - 3540) * 256 + threadIdx.x;
        if (idx >= 40960) return;
        float v = 0.f;
        if (idx < 31744) {
            int j = idx & 7, lane = (idx >> 3) & 63, s = (idx >> 9) & 1, c = idx >> 10;
            int q = lane >> 4;
            int oc = s * 16 + (lane & 15);
            int r = 2 * c + (q >> 1), h = q & 1, kw = 8 * h + j;
            if (oc < 24 && r < 61 && kw < 11) {
                int kd = r / 11, kh = r % 11;
                int tap = kd * 121 + kh * 11 + kw;
                if (tap < 665) v = W1[oc * 1331 + tap];
            }
        } else if (idx < 33280) {
            int i2 = idx - 31744;
            int j = i2 & 7, lane = (i2 >> 3) & 63, t = i2 >> 9;
            int m = t * 16 + (lane & 15), k = (lane >> 4) * 8 + j;
            if (k < 25) v = Wa[m * 25 + k];
            else if (k == 25) {
                float s = ba[m];
                for (int c = 0; c < 24; ++c) s += Wa[m * 25 + c] * b1[c];
                v = s;
            }
        } else if (idx < 39424) {
            int i3 = idx - 33280;
            int j = i3 & 7, lane = (i3 >> 3) & 63, k2 = (i3 >> 9) & 1, s = i3 >> 10;
            int m = s * 16 + (lane & 15), ch = k2 * 32 + (lane >> 4) * 8 + j;
            if (ch < 48) v = Wb[m * 48 + ch];
            else if (ch == 48) v = bb[m];
        } else {
            int i4 = idx - 39424;
            int j = i4 & 7, lane = (i4 >> 3) & 63, k3 = i4 >> 9;
            int m = lane & 15, ch = k3 * 32 + (lane >> 4) * 8 + j;
            if (m < 9) v = Wc[m * 96 + ch];
        }
        pk[idx] = f2h(v);
    } else {                               // ---- xhp: padded fp16 volume
        int idx = (bx - 3700) * 256 + threadIdx.x;   // 187456 uint2
        if (idx >= 187456) return;
        int si = idx * 4;
        int zp = si / 3712, rem = si - zp * 3712;
        int yp = rem >> 6, xp0 = rem & 63;
        float f[4];
#pragma unroll
        for (int k = 0; k < 4; ++k) {
            int xp = xp0 + k;
            bool in = zp >= 5 && zp < 197 && yp >= 5 && yp < 53 && xp >= 5 && xp < 53;
            f[k] = in ? xg[(size_t)(zp - 5) * HW + (yp - 5) * 48 + (xp - 5)] : 0.f;
        }
        *(uint2*)&xhp[si] = make_uint2(pk2(f[0], f[1]), pk2(f[2], f[3]));
    }
}

// ---------------- fused3: conv2d(in-block) + conv3d + MLP + likelihood --------
// 1728 blocks x 256 thr. Block tile: 16 d x 4 y x 4 x. Wave w <-> y row.
// LDS 36864 B -> 4 blocks/CU; launch_bounds(256,4) caps VGPR at 128 to match.
__global__ __launch_bounds__(256, 4) void fused3(const unsigned short* __restrict__ xhp,
                                                 const unsigned short* __restrict__ pk,
                                                 const unsigned short* __restrict__ hyperTp,
                                                 const unsigned short* __restrict__ apack,
                                                 const float* __restrict__ b3,
                                                 const float* __restrict__ xg,
                                                 const float* __restrict__ bc,
                                                 float* __restrict__ out) {
    // P: patch (294 rows x 16 sh = 4704) then acc staging [64 pos][104] (6656);
    //    oacs (9 f32/pos) overlays each pos's dead b0 segment during the MLP.
    __shared__ __align__(16) unsigned short P[6656];        // 13312 B
    // U: early phase = hpart (1024 f32 = 4096 B); MLP phase = t1s[4][1152] + t2s[4][1664]
    __shared__ __align__(16) unsigned short U[11264];       // 22528 B
    __shared__ __align__(16) float htile[256];              // 1024 B

    const int tid = threadIdx.x, w = tid >> 6, lane = tid & 63;
    const int n = lane & 15, q = lane >> 4;
    const int bx = blockIdx.x;
    const int x0 = (bx % 12) * 4, y0 = ((bx / 12) % 12) * 4;
    const int T = bx / 144, d0 = T * 16;

    float* hpart = (float*)U;

    // ---- stage conv3d patch: 294 rows x 2 uint4 (row = py*21+pz, 16 shorts)
#pragma unroll
    for (int k = 0; k < 3; ++k) {
        int idx = tid + k * 256;
        if (idx < 588) {
            int row = idx >> 1, half = idx & 1;
            int py = row / 21, pz = row - py * 21;
            const uint4* src = (const uint4*)(xhp + ((size_t)(d0 + pz) * 58 + (y0 + py)) * 64
                                              + x0 + half * 8);
            *(uint4*)&P[row * 16 + half * 8] = *src;
        }
    }

    // ---- conv2d partials: wave w handles ic-groups c = 3w..3w+2 (16 oc x 16 px)
    {
        f32x4 hacc = {0.f, 0.f, 0.f, 0.f};
        const int pp = (y0 + (n >> 2)) * 50 + x0 + (n & 3);   // pos n = (yloc, xloc)
        const size_t bbase = (size_t)pp * 384 + q * 8;
#pragma unroll
        for (int cc = 0; cc < 3; ++cc) {
            const int c = w * 3 + cc;
            const unsigned short* ap = apack + ((size_t)(T * 12 + c) * 9) * 512 + lane * 8;
            const int coff = c * 32;
#pragma unroll
            for (int t = 0; t < 9; ++t) {
                f16x8 a = *(const f16x8*)(ap + t * 512);
                const int dd = (t / 3) * 50 + (t % 3);        // compile-time
                f16x8 b = *(const f16x8*)(hyperTp + bbase + (size_t)dd * 384 + coff);
                hacc = __builtin_amdgcn_mfma_f32_16x16x32_f16(a, b, hacc, 0, 0, 0);
            }
        }
#pragma unroll
        for (int e = 0; e < 4; ++e)
            hpart[w * 256 + (q * 4 + e) * 16 + n] = hacc[e];   // hpart[w][oc][pos]
    }
    __syncthreads();   // patch staged + hpart complete

    // ---- htile reduce: one (oc,pos) per thread; + b3 fold
    {
        const int oc = tid >> 4, pos = tid & 15;
        float h = b3[d0 + oc];
#pragma unroll
        for (int ww = 0; ww < 4; ++ww) h += hpart[ww * 256 + oc * 16 + pos];
        htile[oc * 16 + pos] = h;
    }

    // ---- conv3d main loop, FULLY UNROLLED: c compile-time => kd/kh constants,
    //      LDS addr = laneBase + cndmask(two inline consts), A-loads base+imm.
    const f32x4 zf = {0.f, 0.f, 0.f, 0.f};
    f32x4 acc[4][2];
#pragma unroll
    for (int p = 0; p < 4; ++p) { acc[p][0] = zf; acc[p][1] = zf; }

    const f16x8* Av = (const f16x8*)pk;
    const int par = q >> 1;                               // lane parity selector
    const unsigned short* Pb = P + (w * 21 + n) * 16 + (q & 1) * 8;
#pragma unroll
    for (int c = 0; c < 31; ++c) {
        const int r0 = 2 * c, r1 = 2 * c + 1;
        const int o0 = ((r0 % 11) * 21 + (r0 / 11)) * 16; // compile-time
        const int o1 = ((r1 % 11) * 21 + (r1 / 11)) * 16; // compile-time
        const unsigned short* rp = Pb + (par ? o1 : o0);
        unsigned int u[6];
        *(uint4*)&u[0] = *(const uint4*)rp;
        *(uint2*)&u[4] = *(const uint2*)(rp + 8);
        f16x8 ca0 = Av[c * 128 + lane];
        f16x8 ca1 = Av[c * 128 + 64 + lane];
#pragma unroll
        for (int px = 0; px < 4; ++px) {
            unsigned int bw[4];
#pragma unroll
            for (int i = 0; i < 4; ++i) {
                if ((px & 1) == 0) bw[i] = u[(px >> 1) + i];
                else bw[i] = (u[(px >> 1) + i] >> 16) | (u[(px >> 1) + 1 + i] << 16);
            }
            f16x8 bf = *(f16x8*)bw;
            acc[px][0] = __builtin_amdgcn_mfma_f32_16x16x32_f16(ca0, bf, acc[px][0], 0, 0, 0);
            acc[px][1] = __builtin_amdgcn_mfma_f32_16x16x32_f16(ca1, bf, acc[px][1], 0, 0, 0);
        }
    }
    __syncthreads();   // patch consumed; P becomes acc staging

    // ---- stage acc -> P as [64 pos][104]: pos row = w*16+n (wave-local), 24 oc x 4 px
#pragma unroll
    for (int px = 0; px < 4; ++px) {
        unsigned int lo = pk2(acc[px][0][0], acc[px][0][1]);
        unsigned int hi = pk2(acc[px][0][2], acc[px][0][3]);
        *(uint2*)&P[(w * 16 + n) * 104 + px * 24 + q * 4] = make_uint2(lo, hi);
        if (q < 2) {
            unsigned int l2 = pk2(acc[px][1][0], acc[px][1][1]);
            unsigned int h2 = pk2(acc[px][1][2], acc[px][1][3]);
            *(uint2*)&P[(w * 16 + n) * 104 + px * 24 + 16 + q * 4] = make_uint2(l2, h2);
        }
    }
    // everything below is wave-local in LDS: no further barriers needed

    // ---- MLP weights: loaded ONCE (cannot be hoisted above __syncthreads)
    const f16x8* WaF = (const f16x8*)(pk + 31744);
    const f16x8* WbF = (const f16x8*)(pk + 33280);
    const f16x8* WcF = (const f16x8*)(pk + 39424);
    f16x8 waf[3], wbf[12], wcf[3];
#pragma unroll
    for (int s = 0; s < 3; ++s) waf[s] = WaF[s * 64 + lane];
#pragma unroll
    for (int t = 0; t < 12; ++t) wbf[t] = WbF[t * 64 + lane];
#pragma unroll
    for (int k = 0; k < 3; ++k) wcf[k] = WcF[k * 64 + lane];
    float bcv[4];
#pragma unroll
    for (int e = 0; e < 4; ++e) bcv[e] = (q * 4 + e < 9) ? bc[q * 4 + e] : 0.f;

    unsigned short* t1w = U + w * 1152;
    unsigned short* t2w = U + 4608 + w * 1664;
    // t1 const slot: feature 48 = 1.0, 49..63 = 0
    *(uint2*)&t1w[n * 72 + 48 + q * 4] = make_uint2((q == 0) ? 0x00003C00u : 0u, 0u);

    const f16x8 z8 = {};
    for (int px = 0; px < 4; ++px) {
        f16x8 b0;
        if (q < 3) {
            b0 = *(const f16x8*)&P[(w * 16 + n) * 104 + px * 24 + q * 8];
        } else {
            b0 = z8;
            b0[0] = (_Float16)htile[n * 16 + w * 4 + px];   // h feature (k=24)
            b0[1] = (_Float16)1.0f;                          // const (k=25)
        }
        // layer a: 25(+h+const) -> 48
#pragma unroll
        for (int s = 0; s < 3; ++s) {
            f32x4 r1 = __builtin_amdgcn_mfma_f32_16x16x32_f16(waf[s], b0, zf, 0, 0, 0);
            *(uint2*)&t1w[n * 72 + s * 16 + q * 4] =
                make_uint2(pkrtz(fmaxf(r1[0], 0.f), fmaxf(r1[1], 0.f)),
                           pkrtz(fmaxf(r1[2], 0.f), fmaxf(r1[3], 0.f)));
        }
        // layer b: 48(+const) -> 96
        f32x4 rb[6];
#pragma unroll
        for (int s = 0; s < 6; ++s) rb[s] = zf;
#pragma unroll
        for (int k2 = 0; k2 < 2; ++k2) {
            f16x8 bf = *(const f16x8*)&t1w[n * 72 + k2 * 32 + q * 8];
#pragma unroll
            for (int s = 0; s < 6; ++s)
                rb[s] = __builtin_amdgcn_mfma_f32_16x16x32_f16(wbf[s * 2 + k2], bf, rb[s], 0, 0, 0);
        }
#pragma unroll
        for (int s = 0; s < 6; ++s)
            *(uint2*)&t2w[n * 104 + s * 16 + q * 4] =
                make_uint2(pkrtz(fmaxf(rb[s][0], 0.f), fmaxf(rb[s][1], 0.f)),
                           pkrtz(fmaxf(rb[s][2], 0.f), fmaxf(rb[s][3], 0.f)));
        // layer c: 96 -> 9
        f32x4 rc = zf;
#pragma unroll
        for (int k3 = 0; k3 < 3; ++k3) {
            f16x8 bf = *(const f16x8*)&t2w[n * 104 + k3 * 32 + q * 8];
            rc = __builtin_amdgcn_mfma_f32_16x16x32_f16(wcf[k3], bf, rc, 0, 0, 0);
        }
        // oacs: write into this px-group's (now dead) b0 segment of P, as floats
        {
            float* pr = (float*)(P + (w * 16 + n) * 104 + px * 24);
#pragma unroll
            for (int e = 0; e < 4; ++e) {
                const int row = q * 4 + e;
                if (row < 9) pr[row] = rc[e] + bcv[e];
            }
        }
    }

    // ---- likelihood: all 64 lanes, lane l -> pos (d = d0 + l>>2, y = y0+w, x = x0 + (l&3))
    {
        const float* pr = (const float*)(P + (w * 16 + (lane >> 2)) * 104 + (lane & 3) * 24);
        f32x4 oA = *(const f32x4*)pr;
        f32x4 oB = *(const f32x4*)(pr + 4);
        float o8 = pr[8];
        const int gp = (d0 + (lane >> 2)) * HW + (y0 + w) * 48 + x0 + (lane & 3);
        const float xv = xg[gp];
        float m = fmaxf(oB[2], fmaxf(oB[3], o8));
        float e0 = expf(oB[2] - m), e1 = expf(oB[3] - m), e2 = expf(o8 - m);
        float inv_es = 1.0f / (e0 + e1 + e2);
        float mu0 = oA[0], mu1 = oA[1], mu2 = oA[2];
        float s0 = oA[3], s1 = oB[0], s2 = oB[1];
        float p = 0.f;
#pragma unroll
        for (int jj = 0; jj < 3; ++jj) {
            float mu = (jj == 0) ? mu0 : (jj == 1) ? mu1 : mu2;
            float sc = (jj == 0) ? s0 : (jj == 1) ? s1 : s2;
            sc = (sc == 0.0f) ? 1e-9f : sc;
            sc = fabsf(sc);
            float a = phi_f((xv + 0.5f - mu) / sc);
            float b = phi_f((xv - 0.5f - mu) / sc);
            float lik = fabsf(a - b);
            float wgt = ((jj == 0) ? e0 : (jj == 1) ? e1 : e2) * inv_es;
            p = fmaf(wgt, lik, p);
        }
        out[gp] = p;
        out[NPOS + (size_t)0 * NPOS + gp] = mu0;
        out[NPOS + (size_t)1 * NPOS + gp] = mu1;
        out[NPOS + (size_t)2 * NPOS + gp] = mu2;
        out[NPOS + (size_t)3 * NPOS + gp] = s0;
        out[NPOS + (size_t)4 * NPOS + gp] = s1;
        out[NPOS + (size_t)5 * NPOS + gp] = s2;
        out[NPOS + (size_t)6 * NPOS + gp] = oB[2];
        out[NPOS + (size_t)7 * NPOS + gp] = oB[3];
        out[NPOS + (size_t)8 * NPOS + gp] = o8;
    }
}

extern "C" void kernel_launch(void* const* d_in, const int* in_sizes, int n_in,
                              void* d_out, int out_size, void* d_ws, size_t ws_size,
                              hipStream_t stream) {
    const float* x     = (const float*)d_in[0];
    const float* hyper = (const float*)d_in[1];
    const float* W3    = (const float*)d_in[2];
    const float* b3    = (const float*)d_in[3];
    const float* W1    = (const float*)d_in[4];
    const float* b1    = (const float*)d_in[5];
    const float* Wa    = (const float*)d_in[6];
    const float* ba    = (const float*)d_in[7];
    const float* Wb    = (const float*)d_in[8];
    const float* bb    = (const float*)d_in[9];
    const float* Wc    = (const float*)d_in[10];
    const float* bc    = (const float*)d_in[11];
    float* out = (float*)d_out;

    unsigned short* hyperTp = (unsigned short*)d_ws;           // 960000 f16
    unsigned short* apack   = hyperTp + 960000;                // 663552 f16
    unsigned short* pk      = apack + 663552;                  // 40960 f16
    unsigned short* xhp     = pk + 40960;                      // 749824 f16 (padded x)

    prep_all<<<4433, 256, 0, stream>>>(hyper, W3, W1, Wa, ba, b1, Wb, bb, Wc, x,
                                       hyperTp, apack, pk, xhp);
    fused3<<<1728, 256, 0, stream>>>(xhp, pk, hyperTp, apack, b3, x, bc, out);
}